// Round 18
// baseline (118.465 us; speedup 1.0000x reference)
//
#include <hip/hip_runtime.h>
#include <hip/hip_bf16.h>
#include <stdint.h>

#define S_SZ 4096
// (1/sqrt(256)) * log2(e): scores come out in exp2 domain
#define SCL 0.09016844005586937f

typedef short bf16x8 __attribute__((ext_vector_type(8)));
typedef float f32x4 __attribute__((ext_vector_type(4)));
typedef float f32x16 __attribute__((ext_vector_type(16)));
typedef unsigned short u16;
typedef unsigned int u32;

#define MFMA16(a,b,c) __builtin_amdgcn_mfma_f32_16x16x32_bf16(a,b,c,0,0,0)
#define MFMA32(a,b,c) __builtin_amdgcn_mfma_f32_32x32x16_bf16(a,b,c,0,0,0)

// HW packed f32->bf16 (RNE): dst = bf(lo) | bf(hi)<<16
__device__ __forceinline__ u32 cvtpk(float lo, float hi){
    u32 r;
    asm("v_cvt_pk_bf16_f32 %0, %1, %2" : "=v"(r) : "v"(lo), "v"(hi));
    return r;
}
__device__ __forceinline__ u16 cvt1(float a){ return (u16)cvtpk(a, a); }

__device__ __forceinline__ void async16(const void* g, void* l){
    __builtin_amdgcn_global_load_lds(
        (const __attribute__((address_space(1))) unsigned int*)g,
        (__attribute__((address_space(3))) unsigned int*)l, 16, 0, 0);
}

// ---------------- weight transpose + cast: Wt[p][dout][din] = bf16(W[din][dout]) -----------
__global__ void wconv_kernel(const float* __restrict__ Wq, const float* __restrict__ Wk,
                             const float* __restrict__ Wv, u16* __restrict__ Wt){
    int idx = blockIdx.x*256 + threadIdx.x;       // 0..196607
    int p = idx >> 16; int rem = idx & 65535;
    int dout = rem >> 8, din = rem & 255;
    const float* W = (p==0) ? Wq : ((p==1) ? Wk : Wv);
    Wt[idx] = cvt1(W[din*256 + dout]);
}

// ---------------- fused projections: one kernel, 3 slabs of 128 blocks ----------------------
// 512 thr = 8 waves x 16 rows (128 rows/block) -> W panel staged ONCE per 128 rows
// (halves W L2 traffic vs 64-row blocks). W staged in 32KB quarters (pre-swizzled
// async16 source; XOR reads).
// p=0: Q row-major [row][256], scaled
// p=1: K d-grouped [b][d>>3][s(4096)][d&7]
// p=2: V grouped   [b][s>>3][256][s&7]
__global__ __launch_bounds__(512)
void proj_all_kernel(const float* __restrict__ Xq, const float* __restrict__ Xk,
                     const float* __restrict__ Xv, const u16* __restrict__ Wt,
                     const float* __restrict__ bq, const float* __restrict__ bk,
                     const float* __restrict__ bv,
                     u16* __restrict__ Qb, u16* __restrict__ Kb, u16* __restrict__ Vt){
    __shared__ char wlds[32768];                  // 64 dout rows x 512B (swizzled)
    int tid = threadIdx.x;
    int bid = blockIdx.x;
    int p = bid >> 7;                             // 128 blocks per slab
    const float* X    = (p==0) ? Xq : ((p==1) ? Xk : Xv);
    const float* bias = (p==0) ? bq : ((p==1) ? bk : bv);
    u16* Out          = (p==0) ? Qb : ((p==1) ? Kb : Vt);
    const char* Wbyte = (const char*)Wt + (size_t)p*131072;
    float scale = (p==0) ? SCL : 1.f;

    int w = tid >> 6, lane = tid & 63;
    int lr = lane & 15, lg = lane >> 4;
    int r0 = (bid & 127) * 128 + w * 16;          // this wave's 16 rows

    bf16x8 a[8];
    #pragma unroll
    for (int ks = 0; ks < 8; ++ks){
        const float* src = X + (size_t)(r0 + lr)*256 + ks*32 + lg*8;
        float4 f0 = *(const float4*)src;
        float4 f1 = *(const float4*)(src+4);
        union { u32 wd[4]; bf16x8 v; } u;
        u.wd[0] = cvtpk(f0.x, f0.y);
        u.wd[1] = cvtpk(f0.z, f0.w);
        u.wd[2] = cvtpk(f1.x, f1.y);
        u.wd[3] = cvtpk(f1.z, f1.w);
        a[ks] = u.v;
    }

    for (int qtr = 0; qtr < 4; ++qtr){
        if (qtr) __syncthreads();                 // all waves done reading before overwrite
        const char* wsrc = Wbyte + qtr*32768;
        #pragma unroll
        for (int i = 0; i < 4; ++i){              // 512 thr x 16B x 4 = 32KB
            int o = i*8192 + tid*16;
            int dout = o >> 9, db = o & 511;
            async16(wsrc + ((dout<<9) | (db ^ ((dout&7)<<4))), wlds + o);
        }
        __syncthreads();                          // staging complete (vmcnt drained)

        #pragma unroll
        for (int dtl = 0; dtl < 4; ++dtl){
            int dt = qtr*4 + dtl;
            int dout_l = dtl*16 + lr;
            f32x4 acc = {0.f,0.f,0.f,0.f};
            #pragma unroll
            for (int ks = 0; ks < 8; ++ks){
                bf16x8 b = *(const bf16x8*)(wlds + dout_l*512 + ((ks*64 + lg*16) ^ ((dout_l&7)<<4)));
                acc = MFMA16(a[ks], b, acc);
            }
            float bv_ = bias[dt*16 + lr];
            int d = dt*16 + lr;
            if (p == 0){
                #pragma unroll
                for (int r = 0; r < 4; ++r){
                    int row = r0 + lg*4 + r;
                    Out[(size_t)row*256 + d] = cvt1((acc[r] + bv_)*scale);
                }
            } else if (p == 2){
                int row = r0 + lg*4;              // 4 consecutive s rows
                int bb = row >> 12;
                int s  = row & 4095;
                union { u32 wd[2]; ushort4 v; } u;
                u.wd[0] = cvtpk(acc[0]+bv_, acc[1]+bv_);
                u.wd[1] = cvtpk(acc[2]+bv_, acc[3]+bv_);
                u16* dst = Out + (size_t)bb*1048576 + (size_t)(s>>3)*2048 + d*8 + (s&7);
                *(ushort4*)dst = u.v;
            } else {
                int row = r0 + lg*4;
                int bb = row >> 12;
                int s  = row & 4095;
                u16* dst = Out + (size_t)bb*1048576 + (size_t)(d>>3)*32768 + (size_t)s*8 + (d&7);
                #pragma unroll
                for (int r = 0; r < 4; ++r)
                    dst[r*8] = cvt1(acc[r]+bv_);
            }
        }
    }
}

// ---------------- flash attention, kv-split partials ---------------------------------------
// grid 256 (XCD-aware), block 512 = 8 waves x 32 q rows (256 q rows/block), 1 block/CU.
// Swapped-operand 32x32x16. R14 schedule (best measured): per iter ch:
//   STAGE(ch+2) -> wait vmcnt(8) [batch(ch) done; ch+1,ch+2 in flight] -> s_barrier ->
//   QK(ch) -> softmax/pack -> PV(ch).  4-deep K/V buffers; never vmcnt(0) mid-loop.
// Prologue: STAGE(0),STAGE(1) BEFORE qf loads; full drain => in-loop counting exact.
#define CH_ROWS 32
#define NCH     32          /* 1024 kv rows per split / 32 */

__global__ __launch_bounds__(512, 2)
void attn_kernel(const u16* __restrict__ Qb, const u16* __restrict__ Kb,
                 const u16* __restrict__ Vt, u16* __restrict__ Opart,
                 float* __restrict__ Mpart, float* __restrict__ Lpart){
    __shared__ char lds[131072];   // K: 4x16KB @0; V: 4x16KB @65536
    int tid = threadIdx.x;
    int w = tid >> 6, lane = tid & 63;
    int q5 = lane & 31, hi = lane >> 5;

    // XCD-aware decode: same (bb,split) combo stays on one XCD for L2 reuse
    int bid = blockIdx.x;
    int xcd = bid & 7;
    int loc = bid >> 3;                 // 0..31
    int combo = xcd*2 + (loc >> 4);     // 0..15
    int qb = loc & 15;
    int bb = combo >> 2;
    int split = combo & 3;
    int qrow0 = qb*256 + w*32;

    const char* Qbyte = (const char*)Qb + (size_t)bb*2097152;
    const char* Kbyte = (const char*)Kb + (size_t)bb*2097152;  // [d>>3][s][d&7]
    const char* Vbyte = (const char*)Vt + (size_t)bb*2097152;  // [s>>3][256][s&7]

    int kv0 = split*1024;

    // stage chunk c into k[c&3], v[c&3]: 4 async16/thread (2 K + 2 V)
    auto STAGE = [&](int c){
        char* Kd = lds + (c&3)*16384;
        char* Vd = lds + 65536 + (c&3)*16384;
        int kv = kv0 + c*CH_ROWS;
        #pragma unroll
        for (int i = 0; i < 2; ++i){
            int o = i*8192 + tid*16;
            async16(Kbyte + ((size_t)(o>>9)*65536 + (size_t)kv*16 + (o&511)), Kd + o);
        }
        #pragma unroll
        for (int i = 0; i < 2; ++i){
            int o = i*8192 + tid*16;
            async16(Vbyte + (size_t)kv*512 + o, Vd + o);
        }
    };

    // ---- prologue: staging first (HBM latency overlaps Q loads), then Q frags, then drain
    STAGE(0);
    STAGE(1);

    bf16x8 qf[16];
    #pragma unroll
    for (int c = 0; c < 16; ++c)
        qf[c] = *(const bf16x8*)(Qbyte + (size_t)(qrow0 + q5)*512 + c*32 + hi*16);
    // Full drain: Q frags + batches 0,1 complete; in-loop vmcnt tracks later batches only.
    asm volatile("s_waitcnt vmcnt(0)" ::: "memory");

    f32x16 acc[8];
    #pragma unroll
    for (int dt=0;dt<8;++dt)
        #pragma unroll
        for (int i=0;i<16;++i) acc[dt][i] = 0.f;
    float m = -1e30f, ls = 0.f;

    for (int ch = 0; ch < NCH; ++ch){
        if (ch + 2 < NCH) STAGE(ch + 2);
        // counted wait: own batch(ch) complete; batches ch+1, ch+2 stay in flight
        if (ch < NCH-2)       { asm volatile("s_waitcnt vmcnt(8)" ::: "memory"); }
        else if (ch == NCH-2) { asm volatile("s_waitcnt vmcnt(4)" ::: "memory"); }
        else                  { asm volatile("s_waitcnt vmcnt(0)" ::: "memory"); }
        __builtin_amdgcn_sched_barrier(0);
        __builtin_amdgcn_s_barrier();     // all waves' batch(ch) now visible in LDS
        __builtin_amdgcn_sched_barrier(0);

        char* Kl = lds + (ch&3)*16384;
        char* Vl = lds + 65536 + (ch&3)*16384;

        // ---- QK^T (swapped): sc = S^T[kv32][q32], depth 256 in 16 chunks
        f32x16 sc;
        #pragma unroll
        for (int i=0;i<16;++i) sc[i] = 0.f;
        __builtin_amdgcn_s_setprio(1);
        #pragma unroll
        for (int c = 0; c < 16; ++c){
            bf16x8 kf = *(const bf16x8*)(Kl + (2*c + hi)*512 + q5*16);
            sc = MFMA32(kf, qf[c], sc);
        }
        __builtin_amdgcn_s_setprio(0);

        // ---- softmax (exp2 domain; defer-max THR=8; lane-local + shfl)
        float x0 = fmaxf(sc[0], sc[1]),  x1 = fmaxf(sc[2], sc[3]);
        float x2 = fmaxf(sc[4], sc[5]),  x3 = fmaxf(sc[6], sc[7]);
        float x4 = fmaxf(sc[8], sc[9]),  x5 = fmaxf(sc[10], sc[11]);
        float x6 = fmaxf(sc[12], sc[13]),x7 = fmaxf(sc[14], sc[15]);
        float lmax = fmaxf(fmaxf(fmaxf(x0,x1), fmaxf(x2,x3)),
                           fmaxf(fmaxf(x4,x5), fmaxf(x6,x7)));
        float pm = fmaxf(lmax, __shfl_xor(lmax, 32));
        if (__any(pm > m + 8.0f)){
            float mn = fmaxf(m, pm);
            float alpha = __builtin_amdgcn_exp2f(m - mn);
            m = mn;
            ls *= alpha;
            #pragma unroll
            for (int dt=0;dt<8;++dt) acc[dt] *= alpha;
        }
        float p[16];
        #pragma unroll
        for (int i=0;i<16;++i) p[i] = __builtin_amdgcn_exp2f(sc[i] - m);
        ls += ((p[0]+p[1])+(p[2]+p[3])) + ((p[4]+p[5])+(p[6]+p[7]))
            + ((p[8]+p[9])+(p[10]+p[11])) + ((p[12]+p[13])+(p[14]+p[15]));

        // ---- pack P^T B-frags (kv halves via shfl_xor 32 — proven mapping)
        bf16x8 pf0, pf1;
        {
            u32 A0 = cvtpk(p[0],p[1]), A1 = cvtpk(p[2],p[3]);
            u32 B0 = cvtpk(p[4],p[5]), B1 = cvtpk(p[6],p[7]);
            u32 XA0 = __shfl_xor(A0, 32), XA1 = __shfl_xor(A1, 32);
            u32 XB0 = __shfl_xor(B0, 32), XB1 = __shfl_xor(B1, 32);
            union { u32 wd[4]; bf16x8 v; } uu;
            uu.wd[0] = hi ? XB0 : A0;
            uu.wd[1] = hi ? XB1 : A1;
            uu.wd[2] = hi ? B0  : XA0;
            uu.wd[3] = hi ? B1  : XA1;
            pf0 = uu.v;
        }
        {
            u32 A0 = cvtpk(p[8],p[9]),   A1 = cvtpk(p[10],p[11]);
            u32 B0 = cvtpk(p[12],p[13]), B1 = cvtpk(p[14],p[15]);
            u32 XA0 = __shfl_xor(A0, 32), XA1 = __shfl_xor(A1, 32);
            u32 XB0 = __shfl_xor(B0, 32), XB1 = __shfl_xor(B1, 32);
            union { u32 wd[4]; bf16x8 v; } uu;
            uu.wd[0] = hi ? XB0 : A0;
            uu.wd[1] = hi ? XB1 : A1;
            uu.wd[2] = hi ? B0  : XA0;
            uu.wd[3] = hi ? B1  : XA1;
            pf1 = uu.v;
        }

        // ---- PV: acc[dt] += mfma(V^T-frag, P^T-frag)
        __builtin_amdgcn_s_setprio(1);
        #pragma unroll
        for (int dt=0; dt<8; ++dt){
            bf16x8 vf = *(const bf16x8*)(Vl + hi*4096 + (dt*32 + q5)*16);
            acc[dt] = MFMA32(vf, pf0, acc[dt]);
        }
        #pragma unroll
        for (int dt=0; dt<8; ++dt){
            bf16x8 vf = *(const bf16x8*)(Vl + (2 + hi)*4096 + (dt*32 + q5)*16);
            acc[dt] = MFMA32(vf, pf1, acc[dt]);
        }
        __builtin_amdgcn_s_setprio(0);
        // no end-of-iter barrier: next iter's barrier bounds skew
    }

    // ---- finalize l (cross-half sum), write partials (bf16 Opart)
    float l = ls + __shfl_xor(ls, 32);

    size_t pbase = (size_t)(split*4 + bb)*S_SZ*256;
    u16* orow = Opart + pbase + (size_t)(qrow0 + q5)*256;
    #pragma unroll
    for (int dt=0; dt<8; ++dt){
        #pragma unroll
        for (int g=0; g<4; ++g){
            int d0 = dt*32 + g*8 + hi*4;
            union { u32 wd[2]; uint2 v; } u2;
            u2.wd[0] = cvtpk(acc[dt][4*g+0], acc[dt][4*g+1]);
            u2.wd[1] = cvtpk(acc[dt][4*g+2], acc[dt][4*g+3]);
            *(uint2*)(orow + d0) = u2.v;
        }
    }
    if (lane < 32){
        int row = qrow0 + q5;
        Mpart[(split*4+bb)*S_SZ + row] = m;
        Lpart[(split*4+bb)*S_SZ + row] = l;
    }
}

// ---------------- combine kv-split partials -------------------------------------------------
__device__ __forceinline__ float bf2f(u16 x){
    union { u32 u; float f; } v; v.u = ((u32)x) << 16; return v.f;
}
__global__ void combine_kernel(const u16* __restrict__ Opart, const float* __restrict__ Mpart,
                               const float* __restrict__ Lpart, float* __restrict__ out){
    int idx = blockIdx.x*256 + threadIdx.x;       // one float4 per thread
    int d4 = (idx & 63)*4;
    int row = idx >> 6;                            // b*4096 + s
    int bb = row >> 12, srow = row & 4095;
    float m[4], lv[4];
    #pragma unroll
    for (int i=0;i<4;++i){
        m[i]  = Mpart[(i*4+bb)*S_SZ + srow];
        lv[i] = Lpart[(i*4+bb)*S_SZ + srow];
    }
    float M = fmaxf(fmaxf(m[0],m[1]), fmaxf(m[2],m[3]));
    float L = 0.f; float wt[4];
    #pragma unroll
    for (int i=0;i<4;++i){ wt[i] = __builtin_amdgcn_exp2f(m[i]-M); L += lv[i]*wt[i]; }
    float inv = 1.f/L;
    float ox=0.f, oy=0.f, oz=0.f, ow=0.f;
    #pragma unroll
    for (int i=0;i<4;++i){
        ushort4 oi = *(const ushort4*)(Opart + (size_t)(i*4+bb)*S_SZ*256 + (size_t)srow*256 + d4);
        ox += bf2f(oi.x)*wt[i]; oy += bf2f(oi.y)*wt[i];
        oz += bf2f(oi.z)*wt[i]; ow += bf2f(oi.w)*wt[i];
    }
    float4 o; o.x = ox*inv; o.y = oy*inv; o.z = oz*inv; o.w = ow*inv;
    *(float4*)(out + (size_t)row*256 + d4) = o;
}

extern "C" void kernel_launch(void* const* d_in, const int* in_sizes, int n_in,
                              void* d_out, int out_size, void* d_ws, size_t ws_size,
                              hipStream_t stream) {
    const float* q_in = (const float*)d_in[0];
    const float* k_in = (const float*)d_in[1];
    const float* v_in = (const float*)d_in[2];
    const float* Wq   = (const float*)d_in[3];
    const float* bq   = (const float*)d_in[4];
    const float* Wk   = (const float*)d_in[5];
    const float* bk   = (const float*)d_in[6];
    const float* Wv   = (const float*)d_in[7];
    const float* bv   = (const float*)d_in[8];

    char* ws = (char*)d_ws;
    u16*  Qb    = (u16*)ws;                         // 8,388,608 B
    u16*  Kb    = (u16*)(ws + 8388608);             // 8,388,608 B
    u16*  Vt    = (u16*)(ws + 16777216);            // 8,388,608 B
    u16*  Wt    = (u16*)(ws + 25165824);            // 393,216 B
    u16*  Opart = (u16*)(ws + 33554432);            // 33,554,432 B (bf16)
    float* Mpart = (float*)(ws + 67108864);         // 262,144 B
    float* Lpart = (float*)(ws + 67371008);         // 262,144 B
    float* out   = (float*)d_out;

    hipLaunchKernelGGL(wconv_kernel,    dim3(768),  dim3(256), 0, stream, Wq, Wk, Wv, Wt);
    hipLaunchKernelGGL(proj_all_kernel, dim3(384),  dim3(512), 0, stream,
                       q_in, k_in, v_in, Wt, bq, bk, bv, Qb, Kb, Vt);
    hipLaunchKernelGGL(attn_kernel,     dim3(256),  dim3(512), 0, stream, Qb, Kb, Vt, Opart, Mpart, Lpart);
    hipLaunchKernelGGL(combine_kernel,  dim3(4096), dim3(256), 0, stream, Opart, Mpart, Lpart, out);
}

// Round 19
// 116.165 us; speedup vs baseline: 1.0198x; 1.0198x over previous
//
#include <hip/hip_runtime.h>
#include <hip/hip_bf16.h>
#include <stdint.h>

#define S_SZ 4096
// (1/sqrt(256)) * log2(e): scores come out in exp2 domain
#define SCL 0.09016844005586937f

typedef short bf16x8 __attribute__((ext_vector_type(8)));
typedef float f32x4 __attribute__((ext_vector_type(4)));
typedef float f32x16 __attribute__((ext_vector_type(16)));
typedef unsigned short u16;
typedef unsigned int u32;

#define MFMA16(a,b,c) __builtin_amdgcn_mfma_f32_16x16x32_bf16(a,b,c,0,0,0)
#define MFMA32(a,b,c) __builtin_amdgcn_mfma_f32_32x32x16_bf16(a,b,c,0,0,0)

// HW packed f32->bf16 (RNE): dst = bf(lo) | bf(hi)<<16
__device__ __forceinline__ u32 cvtpk(float lo, float hi){
    u32 r;
    asm("v_cvt_pk_bf16_f32 %0, %1, %2" : "=v"(r) : "v"(lo), "v"(hi));
    return r;
}
__device__ __forceinline__ u16 cvt1(float a){ return (u16)cvtpk(a, a); }

__device__ __forceinline__ void async16(const void* g, void* l){
    __builtin_amdgcn_global_load_lds(
        (const __attribute__((address_space(1))) unsigned int*)g,
        (__attribute__((address_space(3))) unsigned int*)l, 16, 0, 0);
}

// ---------------- weight transpose + cast: Wt[p][dout][din] = bf16(W[din][dout]) -----------
__global__ void wconv_kernel(const float* __restrict__ Wq, const float* __restrict__ Wk,
                             const float* __restrict__ Wv, u16* __restrict__ Wt){
    int idx = blockIdx.x*256 + threadIdx.x;       // 0..196607
    int p = idx >> 16; int rem = idx & 65535;
    int dout = rem >> 8, din = rem & 255;
    const float* W = (p==0) ? Wq : ((p==1) ? Wk : Wv);
    Wt[idx] = cvt1(W[din*256 + dout]);
}

// ---------------- fused projections: one kernel, 3 slabs of 128 blocks ----------------------
// 512 thr = 8 waves x 16 rows (128 rows/block). W panel double-buffered in LDS
// (stage quarter q+1 while computing q; ONE sync per quarter — R4-proven pattern).
// p=0: Q row-major [row][256], scaled
// p=1: K d-grouped [b][d>>3][s(4096)][d&7]
// p=2: V grouped   [b][s>>3][256][s&7]
__global__ __launch_bounds__(512)
void proj_all_kernel(const float* __restrict__ Xq, const float* __restrict__ Xk,
                     const float* __restrict__ Xv, const u16* __restrict__ Wt,
                     const float* __restrict__ bq, const float* __restrict__ bk,
                     const float* __restrict__ bv,
                     u16* __restrict__ Qb, u16* __restrict__ Kb, u16* __restrict__ Vt){
    __shared__ char wlds[65536];                  // 2 x (64 dout rows x 512B, swizzled)
    int tid = threadIdx.x;
    int bid = blockIdx.x;
    int p = bid >> 7;                             // 128 blocks per slab
    const float* X    = (p==0) ? Xq : ((p==1) ? Xk : Xv);
    const float* bias = (p==0) ? bq : ((p==1) ? bk : bv);
    u16* Out          = (p==0) ? Qb : ((p==1) ? Kb : Vt);
    const char* Wbyte = (const char*)Wt + (size_t)p*131072;
    float scale = (p==0) ? SCL : 1.f;

    int w = tid >> 6, lane = tid & 63;
    int lr = lane & 15, lg = lane >> 4;
    int r0 = (bid & 127) * 128 + w * 16;          // this wave's 16 rows

    // stage W quarter q into wlds[(q&1)*32768]: 4 async16/thread (512 thr x 16B x 4 = 32KB)
    auto WSTAGE = [&](int q){
        const char* wsrc = Wbyte + q*32768;
        char* dst = wlds + (q&1)*32768;
        #pragma unroll
        for (int i = 0; i < 4; ++i){
            int o = i*8192 + tid*16;
            int dout = o >> 9, db = o & 511;
            async16(wsrc + ((dout<<9) | (db ^ ((dout&7)<<4))), dst + o);
        }
    };

    WSTAGE(0);                                    // quarter 0 in flight under X loads

    bf16x8 a[8];
    #pragma unroll
    for (int ks = 0; ks < 8; ++ks){
        const float* src = X + (size_t)(r0 + lr)*256 + ks*32 + lg*8;
        float4 f0 = *(const float4*)src;
        float4 f1 = *(const float4*)(src+4);
        union { u32 wd[4]; bf16x8 v; } u;
        u.wd[0] = cvtpk(f0.x, f0.y);
        u.wd[1] = cvtpk(f0.z, f0.w);
        u.wd[2] = cvtpk(f1.x, f1.y);
        u.wd[3] = cvtpk(f1.z, f1.w);
        a[ks] = u.v;
    }
    __syncthreads();                              // quarter 0 staged (vmcnt drained)

    for (int qtr = 0; qtr < 4; ++qtr){
        if (qtr + 1 < 4) WSTAGE(qtr + 1);         // prefetch next quarter into buf^1
        const char* wb = wlds + (qtr&1)*32768;

        #pragma unroll
        for (int dtl = 0; dtl < 4; ++dtl){
            int dt = qtr*4 + dtl;
            int dout_l = dtl*16 + lr;
            f32x4 acc = {0.f,0.f,0.f,0.f};
            #pragma unroll
            for (int ks = 0; ks < 8; ++ks){
                bf16x8 b = *(const bf16x8*)(wb + dout_l*512 + ((ks*64 + lg*16) ^ ((dout_l&7)<<4)));
                acc = MFMA16(a[ks], b, acc);
            }
            float bv_ = bias[dt*16 + lr];
            int d = dt*16 + lr;
            if (p == 0){
                #pragma unroll
                for (int r = 0; r < 4; ++r){
                    int row = r0 + lg*4 + r;
                    Out[(size_t)row*256 + d] = cvt1((acc[r] + bv_)*scale);
                }
            } else if (p == 2){
                int row = r0 + lg*4;              // 4 consecutive s rows
                int bb = row >> 12;
                int s  = row & 4095;
                union { u32 wd[2]; ushort4 v; } u;
                u.wd[0] = cvtpk(acc[0]+bv_, acc[1]+bv_);
                u.wd[1] = cvtpk(acc[2]+bv_, acc[3]+bv_);
                u16* dst = Out + (size_t)bb*1048576 + (size_t)(s>>3)*2048 + d*8 + (s&7);
                *(ushort4*)dst = u.v;
            } else {
                int row = r0 + lg*4;
                int bb = row >> 12;
                int s  = row & 4095;
                u16* dst = Out + (size_t)bb*1048576 + (size_t)(d>>3)*32768 + (size_t)s*8 + (d&7);
                #pragma unroll
                for (int r = 0; r < 4; ++r)
                    dst[r*8] = cvt1(acc[r]+bv_);
            }
        }
        __syncthreads();   // next quarter staged (vmcnt drained) + all waves done with buf
    }
}

// ---------------- flash attention, kv-split partials ---------------------------------------
// grid 256 (XCD-aware), block 512 = 8 waves x 32 q rows (256 q rows/block), 1 block/CU.
// Swapped-operand 32x32x16. R14 schedule (best measured): per iter ch:
//   STAGE(ch+2) -> wait vmcnt(8) [batch(ch) done; ch+1,ch+2 in flight] -> s_barrier ->
//   QK(ch) -> softmax/pack -> PV(ch).  4-deep K/V buffers; never vmcnt(0) mid-loop.
// Prologue: STAGE(0),STAGE(1) BEFORE qf loads; full drain => in-loop counting exact.
#define CH_ROWS 32
#define NCH     32          /* 1024 kv rows per split / 32 */

__global__ __launch_bounds__(512, 2)
void attn_kernel(const u16* __restrict__ Qb, const u16* __restrict__ Kb,
                 const u16* __restrict__ Vt, u16* __restrict__ Opart,
                 float* __restrict__ Mpart, float* __restrict__ Lpart){
    __shared__ char lds[131072];   // K: 4x16KB @0; V: 4x16KB @65536
    int tid = threadIdx.x;
    int w = tid >> 6, lane = tid & 63;
    int q5 = lane & 31, hi = lane >> 5;

    // XCD-aware decode: same (bb,split) combo stays on one XCD for L2 reuse
    int bid = blockIdx.x;
    int xcd = bid & 7;
    int loc = bid >> 3;                 // 0..31
    int combo = xcd*2 + (loc >> 4);     // 0..15
    int qb = loc & 15;
    int bb = combo >> 2;
    int split = combo & 3;
    int qrow0 = qb*256 + w*32;

    const char* Qbyte = (const char*)Qb + (size_t)bb*2097152;
    const char* Kbyte = (const char*)Kb + (size_t)bb*2097152;  // [d>>3][s][d&7]
    const char* Vbyte = (const char*)Vt + (size_t)bb*2097152;  // [s>>3][256][s&7]

    int kv0 = split*1024;

    // stage chunk c into k[c&3], v[c&3]: 4 async16/thread (2 K + 2 V)
    auto STAGE = [&](int c){
        char* Kd = lds + (c&3)*16384;
        char* Vd = lds + 65536 + (c&3)*16384;
        int kv = kv0 + c*CH_ROWS;
        #pragma unroll
        for (int i = 0; i < 2; ++i){
            int o = i*8192 + tid*16;
            async16(Kbyte + ((size_t)(o>>9)*65536 + (size_t)kv*16 + (o&511)), Kd + o);
        }
        #pragma unroll
        for (int i = 0; i < 2; ++i){
            int o = i*8192 + tid*16;
            async16(Vbyte + (size_t)kv*512 + o, Vd + o);
        }
    };

    // ---- prologue: staging first (HBM latency overlaps Q loads), then Q frags, then drain
    STAGE(0);
    STAGE(1);

    bf16x8 qf[16];
    #pragma unroll
    for (int c = 0; c < 16; ++c)
        qf[c] = *(const bf16x8*)(Qbyte + (size_t)(qrow0 + q5)*512 + c*32 + hi*16);
    // Full drain: Q frags + batches 0,1 complete; in-loop vmcnt tracks later batches only.
    asm volatile("s_waitcnt vmcnt(0)" ::: "memory");

    f32x16 acc[8];
    #pragma unroll
    for (int dt=0;dt<8;++dt)
        #pragma unroll
        for (int i=0;i<16;++i) acc[dt][i] = 0.f;
    float m = -1e30f, ls = 0.f;

    for (int ch = 0; ch < NCH; ++ch){
        if (ch + 2 < NCH) STAGE(ch + 2);
        // counted wait: own batch(ch) complete; batches ch+1, ch+2 stay in flight
        if (ch < NCH-2)       { asm volatile("s_waitcnt vmcnt(8)" ::: "memory"); }
        else if (ch == NCH-2) { asm volatile("s_waitcnt vmcnt(4)" ::: "memory"); }
        else                  { asm volatile("s_waitcnt vmcnt(0)" ::: "memory"); }
        __builtin_amdgcn_sched_barrier(0);
        __builtin_amdgcn_s_barrier();     // all waves' batch(ch) now visible in LDS
        __builtin_amdgcn_sched_barrier(0);

        char* Kl = lds + (ch&3)*16384;
        char* Vl = lds + 65536 + (ch&3)*16384;

        // ---- QK^T (swapped): sc = S^T[kv32][q32], depth 256 in 16 chunks
        f32x16 sc;
        #pragma unroll
        for (int i=0;i<16;++i) sc[i] = 0.f;
        __builtin_amdgcn_s_setprio(1);
        #pragma unroll
        for (int c = 0; c < 16; ++c){
            bf16x8 kf = *(const bf16x8*)(Kl + (2*c + hi)*512 + q5*16);
            sc = MFMA32(kf, qf[c], sc);
        }
        __builtin_amdgcn_s_setprio(0);

        // ---- softmax (exp2 domain; defer-max THR=8; lane-local + shfl)
        float x0 = fmaxf(sc[0], sc[1]),  x1 = fmaxf(sc[2], sc[3]);
        float x2 = fmaxf(sc[4], sc[5]),  x3 = fmaxf(sc[6], sc[7]);
        float x4 = fmaxf(sc[8], sc[9]),  x5 = fmaxf(sc[10], sc[11]);
        float x6 = fmaxf(sc[12], sc[13]),x7 = fmaxf(sc[14], sc[15]);
        float lmax = fmaxf(fmaxf(fmaxf(x0,x1), fmaxf(x2,x3)),
                           fmaxf(fmaxf(x4,x5), fmaxf(x6,x7)));
        float pm = fmaxf(lmax, __shfl_xor(lmax, 32));
        if (__any(pm > m + 8.0f)){
            float mn = fmaxf(m, pm);
            float alpha = __builtin_amdgcn_exp2f(m - mn);
            m = mn;
            ls *= alpha;
            #pragma unroll
            for (int dt=0;dt<8;++dt) acc[dt] *= alpha;
        }
        float p[16];
        #pragma unroll
        for (int i=0;i<16;++i) p[i] = __builtin_amdgcn_exp2f(sc[i] - m);
        ls += ((p[0]+p[1])+(p[2]+p[3])) + ((p[4]+p[5])+(p[6]+p[7]))
            + ((p[8]+p[9])+(p[10]+p[11])) + ((p[12]+p[13])+(p[14]+p[15]));

        // ---- pack P^T B-frags (kv halves via shfl_xor 32 — proven mapping)
        bf16x8 pf0, pf1;
        {
            u32 A0 = cvtpk(p[0],p[1]), A1 = cvtpk(p[2],p[3]);
            u32 B0 = cvtpk(p[4],p[5]), B1 = cvtpk(p[6],p[7]);
            u32 XA0 = __shfl_xor(A0, 32), XA1 = __shfl_xor(A1, 32);
            u32 XB0 = __shfl_xor(B0, 32), XB1 = __shfl_xor(B1, 32);
            union { u32 wd[4]; bf16x8 v; } uu;
            uu.wd[0] = hi ? XB0 : A0;
            uu.wd[1] = hi ? XB1 : A1;
            uu.wd[2] = hi ? B0  : XA0;
            uu.wd[3] = hi ? B1  : XA1;
            pf0 = uu.v;
        }
        {
            u32 A0 = cvtpk(p[8],p[9]),   A1 = cvtpk(p[10],p[11]);
            u32 B0 = cvtpk(p[12],p[13]), B1 = cvtpk(p[14],p[15]);
            u32 XA0 = __shfl_xor(A0, 32), XA1 = __shfl_xor(A1, 32);
            u32 XB0 = __shfl_xor(B0, 32), XB1 = __shfl_xor(B1, 32);
            union { u32 wd[4]; bf16x8 v; } uu;
            uu.wd[0] = hi ? XB0 : A0;
            uu.wd[1] = hi ? XB1 : A1;
            uu.wd[2] = hi ? B0  : XA0;
            uu.wd[3] = hi ? B1  : XA1;
            pf1 = uu.v;
        }

        // ---- PV: acc[dt] += mfma(V^T-frag, P^T-frag)
        __builtin_amdgcn_s_setprio(1);
        #pragma unroll
        for (int dt=0; dt<8; ++dt){
            bf16x8 vf = *(const bf16x8*)(Vl + hi*4096 + (dt*32 + q5)*16);
            acc[dt] = MFMA32(vf, pf0, acc[dt]);
        }
        #pragma unroll
        for (int dt=0; dt<8; ++dt){
            bf16x8 vf = *(const bf16x8*)(Vl + (2 + hi)*4096 + (dt*32 + q5)*16);
            acc[dt] = MFMA32(vf, pf1, acc[dt]);
        }
        __builtin_amdgcn_s_setprio(0);
        // no end-of-iter barrier: next iter's barrier bounds skew
    }

    // ---- finalize l (cross-half sum), write partials (bf16 Opart)
    float l = ls + __shfl_xor(ls, 32);

    size_t pbase = (size_t)(split*4 + bb)*S_SZ*256;
    u16* orow = Opart + pbase + (size_t)(qrow0 + q5)*256;
    #pragma unroll
    for (int dt=0; dt<8; ++dt){
        #pragma unroll
        for (int g=0; g<4; ++g){
            int d0 = dt*32 + g*8 + hi*4;
            union { u32 wd[2]; uint2 v; } u2;
            u2.wd[0] = cvtpk(acc[dt][4*g+0], acc[dt][4*g+1]);
            u2.wd[1] = cvtpk(acc[dt][4*g+2], acc[dt][4*g+3]);
            *(uint2*)(orow + d0) = u2.v;
        }
    }
    if (lane < 32){
        int row = qrow0 + q5;
        Mpart[(split*4+bb)*S_SZ + row] = m;
        Lpart[(split*4+bb)*S_SZ + row] = l;
    }
}

// ---------------- combine kv-split partials (2 float4 per thread) ---------------------------
__device__ __forceinline__ float bf2f(u16 x){
    union { u32 u; float f; } v; v.u = ((u32)x) << 16; return v.f;
}
__global__ void combine_kernel(const u16* __restrict__ Opart, const float* __restrict__ Mpart,
                               const float* __restrict__ Lpart, float* __restrict__ out){
    int idx = blockIdx.x*256 + threadIdx.x;        // one float8 (2 x float4) per thread
    int d8 = (idx & 31)*8;
    int row = idx >> 5;                            // b*4096 + s
    int bb = row >> 12, srow = row & 4095;
    float m[4], lv[4];
    #pragma unroll
    for (int i=0;i<4;++i){
        m[i]  = Mpart[(i*4+bb)*S_SZ + srow];
        lv[i] = Lpart[(i*4+bb)*S_SZ + srow];
    }
    float M = fmaxf(fmaxf(m[0],m[1]), fmaxf(m[2],m[3]));
    float L = 0.f; float wt[4];
    #pragma unroll
    for (int i=0;i<4;++i){ wt[i] = __builtin_amdgcn_exp2f(m[i]-M); L += lv[i]*wt[i]; }
    float inv = 1.f/L;
    float o[8];
    #pragma unroll
    for (int j=0;j<8;++j) o[j] = 0.f;
    #pragma unroll
    for (int i=0;i<4;++i){
        const u16* src = Opart + (size_t)(i*4+bb)*S_SZ*256 + (size_t)srow*256 + d8;
        ushort4 lo = *(const ushort4*)src;
        ushort4 hi4 = *(const ushort4*)(src + 4);
        o[0] += bf2f(lo.x)*wt[i];  o[1] += bf2f(lo.y)*wt[i];
        o[2] += bf2f(lo.z)*wt[i];  o[3] += bf2f(lo.w)*wt[i];
        o[4] += bf2f(hi4.x)*wt[i]; o[5] += bf2f(hi4.y)*wt[i];
        o[6] += bf2f(hi4.z)*wt[i]; o[7] += bf2f(hi4.w)*wt[i];
    }
    float* dst = out + (size_t)row*256 + d8;
    float4 v0; v0.x = o[0]*inv; v0.y = o[1]*inv; v0.z = o[2]*inv; v0.w = o[3]*inv;
    float4 v1; v1.x = o[4]*inv; v1.y = o[5]*inv; v1.z = o[6]*inv; v1.w = o[7]*inv;
    *(float4*)dst = v0;
    *(float4*)(dst + 4) = v1;
}

extern "C" void kernel_launch(void* const* d_in, const int* in_sizes, int n_in,
                              void* d_out, int out_size, void* d_ws, size_t ws_size,
                              hipStream_t stream) {
    const float* q_in = (const float*)d_in[0];
    const float* k_in = (const float*)d_in[1];
    const float* v_in = (const float*)d_in[2];
    const float* Wq   = (const float*)d_in[3];
    const float* bq   = (const float*)d_in[4];
    const float* Wk   = (const float*)d_in[5];
    const float* bk   = (const float*)d_in[6];
    const float* Wv   = (const float*)d_in[7];
    const float* bv   = (const float*)d_in[8];

    char* ws = (char*)d_ws;
    u16*  Qb    = (u16*)ws;                         // 8,388,608 B
    u16*  Kb    = (u16*)(ws + 8388608);             // 8,388,608 B
    u16*  Vt    = (u16*)(ws + 16777216);            // 8,388,608 B
    u16*  Wt    = (u16*)(ws + 25165824);            // 393,216 B
    u16*  Opart = (u16*)(ws + 33554432);            // 33,554,432 B (bf16)
    float* Mpart = (float*)(ws + 67108864);         // 262,144 B
    float* Lpart = (float*)(ws + 67371008);         // 262,144 B
    float* out   = (float*)d_out;

    hipLaunchKernelGGL(wconv_kernel,    dim3(768),  dim3(256), 0, stream, Wq, Wk, Wv, Wt);
    hipLaunchKernelGGL(proj_all_kernel, dim3(384),  dim3(512), 0, stream,
                       q_in, k_in, v_in, Wt, bq, bk, bv, Qb, Kb, Vt);
    hipLaunchKernelGGL(attn_kernel,     dim3(256),  dim3(512), 0, stream, Qb, Kb, Vt, Opart, Mpart, Lpart);
    hipLaunchKernelGGL(combine_kernel,  dim3(2048), dim3(256), 0, stream, Opart, Mpart, Lpart, out);
}